// Round 12
// baseline (415.750 us; speedup 1.0000x reference)
//
#include <hip/hip_runtime.h>
#include <stdint.h>

#define NB 32
#define SEQ 577
#define SPAD 640
#define NH 16
#define HD 64
#define DM 1024
#define MTOT (NB * SEQ) /* 18464 */
#define NKT 32          /* K-tiles of 32: 1024/32 */

typedef __bf16 bf16x8 __attribute__((ext_vector_type(8)));
typedef float f32x4 __attribute__((ext_vector_type(4)));
typedef unsigned short u16x8 __attribute__((ext_vector_type(8)));
typedef unsigned short u16x4 __attribute__((ext_vector_type(4)));

__device__ __forceinline__ unsigned short f2bf(float f) {
  unsigned int u = __builtin_bit_cast(unsigned int, f);
  return (unsigned short)((u + 0x7FFFu + ((u >> 16) & 1u)) >> 16);
}

__device__ __forceinline__ f32x4 mfma16(bf16x8 a, bf16x8 b, f32x4 c) {
  return __builtin_amdgcn_mfma_f32_16x16x32_bf16(a, b, c, 0, 0, 0);
}

__device__ __forceinline__ void gload16(const unsigned short* g, unsigned short* l) {
  __builtin_amdgcn_global_load_lds(
      (const __attribute__((address_space(1))) unsigned int*)g,
      (__attribute__((address_space(3))) unsigned int*)l, 16, 0, 0);
}

#define BC8(p) __builtin_bit_cast(bf16x8, *(const u16x8*)(p))

#if __has_builtin(__builtin_amdgcn_exp2f)
#define EXP2(x) __builtin_amdgcn_exp2f(x)
#else
#define EXP2(x) exp2f(x)
#endif

// softmax scale folded into Q at projection epilogue: 0.125 * log2(e)
#define QSCALE 0.18033688f

// ---------------- fp32 -> bf16 conversion of x and the 3 weight matrices ----
__global__ void cvt_kernel(const float* __restrict__ x,
                           const float* __restrict__ wq,
                           const float* __restrict__ wk,
                           const float* __restrict__ wv,
                           unsigned short* __restrict__ xb,
                           unsigned short* __restrict__ wb) {
  const long long NX = (long long)MTOT * DM;
  long long i = ((long long)blockIdx.x * blockDim.x + threadIdx.x) * 4;
  const float* src;
  unsigned short* dst;
  if (i < NX) {
    src = x + i;
    dst = xb + i;
  } else {
    long long j = i - NX;                 // 0 .. 3*2^20-1, DM*DM = 2^20
    int wsel = (int)(j >> 20);
    long long off = j & 0xFFFFF;
    src = (wsel == 0 ? wq : wsel == 1 ? wk : wv) + off;
    dst = wb + j;
  }
  f32x4 v = *(const f32x4*)src;
  u16x4 o;
  o.x = f2bf(v.x); o.y = f2bf(v.y); o.z = f2bf(v.z); o.w = f2bf(v.w);
  *(u16x4*)dst = o;
}

// ---------------- 256^2 BK=32 GEMM: 64 KiB LDS -> 2 blocks/CU --------------
// R11: occupancy is the lever. All prior 256^2 variants used 128 KiB LDS ->
// 1 block/CU (2 waves/SIMD): every barrier/vmcnt stall fully exposed, no
// co-resident block to cover it (m114 mechanism). BK=32 halves LDS to
// 64 KiB -> 2 blocks/CU (4 waves/SIMD); cross-block overlap fills stalls.
// Per kt: {stage kt+1 -> other buf; 12 ds_reads; MFMA (compiler-counted
// lgkm); vmcnt(0); barrier}. WAR: staged buffer's readers all passed the
// previous barrier (their reads drained before their last MFMA). RAW:
// vmcnt(0) before barrier, loads had the whole iteration to land.
// Swizzle: 4 chunks/row, store chunk cpos at cpos^(row&3); read chunk
// g^(c&3) (rows used have row&3 == c&3). Residual 4-way conflict accepted.
template <int MODE>
__device__ __forceinline__ void kloop32(
    unsigned short* LDS, const unsigned short* const* gA,
    const unsigned short* const* gB, f32x4 (&acc)[8][4],
    int rA0, int rB0, int chA) {
#define MM(ACC, AF, BF)                                   \
  do {                                                    \
    if constexpr (MODE == 0)                              \
      ACC = mfma16(AF, BF, ACC);                          \
    else                                                  \
      ACC = mfma16(BF, AF, ACC);                          \
  } while (0)
  const int t = threadIdx.x;
  for (int kt = 0; kt < NKT; ++kt) {
    unsigned short* bufc = LDS + (kt & 1) * 16384;
    unsigned short* bufn = LDS + ((kt & 1) ^ 1) * 16384;
    if (kt + 1 < NKT) {
      const int k1 = (kt + 1) * 32;
      gload16(gA[0] + k1, bufn + t * 8);
      gload16(gA[1] + k1, bufn + 4096 + t * 8);
      gload16(gB[0] + k1, bufn + 8192 + t * 8);
      gload16(gB[1] + k1, bufn + 12288 + t * 8);
    }
    bf16x8 af[8], bfr[4];
#pragma unroll
    for (int mi = 0; mi < 8; mi++)
      af[mi] = BC8(bufc + (rA0 + mi * 16) * 32 + chA);
#pragma unroll
    for (int ni = 0; ni < 4; ni++)
      bfr[ni] = BC8(bufc + 8192 + (rB0 + ni * 16) * 32 + chA);
    __builtin_amdgcn_s_setprio(1);
#pragma unroll
    for (int mi = 0; mi < 8; mi++)
#pragma unroll
      for (int ni = 0; ni < 4; ni++) MM(acc[mi][ni], af[mi], bfr[ni]);
    __builtin_amdgcn_s_setprio(0);
    asm volatile("s_waitcnt vmcnt(0)" ::: "memory");
    __builtin_amdgcn_s_barrier();
    __builtin_amdgcn_sched_barrier(0);
  }
#undef MM
}

// ---------------- fused Q/K/V projection (876 blocks) -----------------------
__global__ __launch_bounds__(512, 2) void gemm256u(
    const unsigned short* __restrict__ xb, const unsigned short* __restrict__ wb,
    const float* __restrict__ bq, const float* __restrict__ bk,
    const float* __restrict__ bv,
    unsigned short* __restrict__ qo, unsigned short* __restrict__ ko,
    unsigned short* __restrict__ vo) {
  __shared__ __align__(16) unsigned short LDS[32768];  // 64 KiB
  const int id = blockIdx.x;
  int m_tile, col, z;
  bool modeV;
  if (id < 584) {
    modeV = false;
    const int xcd = id & 7, j = id >> 3;
    const int p = xcd * 73 + j;       // bijective, 0..583
    m_tile = p >> 3;                  // 0..72
    col = p & 7;                      // 0..7 (col&3 -> n-block)
    z = col >> 2;                     // 0: Q, 1: K
  } else {
    modeV = true;
    const int q = id - 584;           // 0..291
    const int xcd = q & 7, j = q >> 3;
    const int p = (xcd < 4) ? xcd * 37 + j : 148 + (xcd - 4) * 36 + j;
    m_tile = p >> 2;                  // 0..72
    col = p & 3;                      // 0..3
    z = 2;
  }
  const int n0 = (modeV ? col : (col & 3)) * 256;
  const int m0 = m_tile * 256;

  const int t = threadIdx.x;        // 0..511
  const int lane = t & 63;
  const int w = t >> 6;             // 8 waves
  const int g = lane >> 4, c = lane & 15;
  const int wm = w & 1, wn = w >> 1;

  const unsigned short* W = wb + (size_t)z * (DM * DM);
  const float* bias = modeV ? bv : (z ? bk : bq);
  unsigned short* outp = modeV ? vo : (z ? ko : qo);
  const float qscale = (!modeV && z == 0) ? QSCALE : 1.0f;

  // staging: thread t covers chunk (row = t>>2, cpos = t&3) of each 128-row
  // half; source chunk index pre-swizzled: scp = cpos ^ (row&3).
  const int srow = t >> 2;          // 0..127
  const int sswz = (t & 3) ^ (srow & 3);
  const unsigned short* gA[2];
  {
    int r0_ = m0 + srow;       if (r0_ > MTOT - 1) r0_ = MTOT - 1;
    int r1_ = m0 + 128 + srow; if (r1_ > MTOT - 1) r1_ = MTOT - 1;
    gA[0] = xb + (size_t)r0_ * DM + sswz * 8;
    gA[1] = xb + (size_t)r1_ * DM + sswz * 8;
  }
  const unsigned short* gB[2];
  gB[0] = W + (size_t)(n0 + srow) * DM + sswz * 8;
  gB[1] = W + (size_t)(n0 + 128 + srow) * DM + sswz * 8;

  const int chA = (g ^ (c & 3)) * 8;  // swizzled read chunk offset (shorts)
  const int rA0 = wm * 128 + c;
  const int rB0 = wn * 64 + c;

  f32x4 acc[8][4];
#pragma unroll
  for (int mi = 0; mi < 8; mi++)
#pragma unroll
    for (int ni = 0; ni < 4; ni++) acc[mi][ni] = (f32x4)0.0f;

  // prologue: stage K-tile 0 -> buf0
  gload16(gA[0], LDS + t * 8);
  gload16(gA[1], LDS + 4096 + t * 8);
  gload16(gB[0], LDS + 8192 + t * 8);
  gload16(gB[1], LDS + 12288 + t * 8);
  asm volatile("s_waitcnt vmcnt(0)" ::: "memory");
  __builtin_amdgcn_s_barrier();
  __builtin_amdgcn_sched_barrier(0);

  if (!modeV)
    kloop32<0>(LDS, gA, gB, acc, rA0, rB0, chA);
  else
    kloop32<1>(LDS, gA, gB, acc, rA0, rB0, chA);

  if (!modeV) {
    float bias4[4];
#pragma unroll
    for (int ni = 0; ni < 4; ni++) bias4[ni] = bias[n0 + wn * 64 + ni * 16 + c];
#pragma unroll
    for (int mi = 0; mi < 8; mi++) {
      int mb = m0 + wm * 128 + mi * 16 + g * 4;
#pragma unroll
      for (int r = 0; r < 4; r++) {
        int m = mb + r;
        if (m >= MTOT) continue;
        int bi = m / SEQ;
        int s = m - bi * SEQ;
#pragma unroll
        for (int ni = 0; ni < 4; ni++) {
          int n = n0 + wn * 64 + ni * 16 + c;
          int hh = n >> 6, dd = n & 63;
          outp[(((size_t)bi * NH + hh) * SPAD + s) * HD + dd] =
              f2bf((acc[mi][ni][r] + bias4[ni]) * qscale);
        }
      }
    }
  } else {
    // C^T: acc[mi][ni] elem (r, lane c): n = n0+wn*64+ni*16+g*4+r,
    // m = m0+wm*128+mi*16+c. Lanes c -> consecutive s (coalesced).
#pragma unroll
    for (int ni = 0; ni < 4; ni++) {
#pragma unroll
      for (int r = 0; r < 4; r++) {
        int n = n0 + wn * 64 + ni * 16 + g * 4 + r;
        int hh = n >> 6, dd = n & 63;
        float bn = bias[n];
#pragma unroll
        for (int mi = 0; mi < 8; mi++) {
          int m = m0 + wm * 128 + mi * 16 + c;
          if (m >= MTOT) continue;
          int bi = m / SEQ;
          int s = m - bi * SEQ;
          outp[(((size_t)bi * NH + hh) * HD + dd) * SPAD + s] =
              f2bf(acc[mi][ni][r] + bn);
        }
      }
    }
  }
}

// ---------------- flash attention v2: dbuf prefetch; setprio REVERTED -------
// R11: setprio removed (R8 A/B: attn ~183 -> ~197 us; 4 barrier-locked
// waves = m190 lockstep regime where setprio is null-to-negative).
// QSCALE fold kept (scores pre-scaled in Q; EXP2 direct).
__global__ __launch_bounds__(256, 3) void attn_kernel(
    const unsigned short* __restrict__ Qb, const unsigned short* __restrict__ Kb,
    const unsigned short* __restrict__ Vt, float* __restrict__ out) {
  __shared__ __align__(16) unsigned short Ks[2][64 * 64];   // [buf][kv][d], swizzled
  __shared__ __align__(16) unsigned short Vs[2][64 * 64];   // [buf][d][kv], swizzled
  __shared__ __align__(16) unsigned short Vones[16 * 64];   // row 0 = 1.0, rest 0
  __shared__ __align__(16) unsigned short Pl[4][16 * 72];
  const int t = threadIdx.x, lane = t & 63, w = t >> 6;
  const int g = lane >> 4, c = lane & 15;

  const int id = blockIdx.x;          // 0..5119
  const int xcd = id & 7;
  const int slot = id >> 3;           // 0..639
  const int qt = slot % 10;
  const int pairIdx = slot / 10;      // 0..63
  const int pair = xcd * 64 + pairIdx;
  const int b = pair >> 4;
  const int h = pair & 15;

  const int q0 = qt * 64 + w * 16;
  const size_t bh = (size_t)b * NH + h;
  const unsigned short* Qp = Qb + bh * SPAD * HD;
  const unsigned short* Kp = Kb + bh * SPAD * HD;
  const unsigned short* Vp = Vt + bh * HD * SPAD;

  {
    int rr = t >> 4, col = (t & 15) * 4;
    unsigned short val = (rr == 0) ? (unsigned short)0x3F80 : (unsigned short)0;
    u16x4 v4 = {val, val, val, val};
    *(u16x4*)(Vones + rr * 64 + col) = v4;
  }

  bf16x8 qf0 = __builtin_bit_cast(
      bf16x8, *(const u16x8*)(Qp + (size_t)(q0 + c) * HD + g * 8));
  bf16x8 qf1 = __builtin_bit_cast(
      bf16x8, *(const u16x8*)(Qp + (size_t)(q0 + c) * HD + 32 + g * 8));

  const int C0 = t, C1 = t + 256;
  const int r0 = C0 >> 3, cg0 = (C0 & 7) ^ (r0 & 7);
  const int r1 = C1 >> 3, cg1 = (C1 & 7) ^ (r1 & 7);
  const unsigned short* gK0 = Kp + (size_t)(r0 * 8 + cg0) * 8;
  const unsigned short* gK1 = Kp + (size_t)(r1 * 8 + cg1) * 8;
  const unsigned short* gV0 = Vp + (size_t)r0 * SPAD + cg0 * 8;
  const unsigned short* gV1 = Vp + (size_t)r1 * SPAD + cg1 * 8;

  f32x4 oacc[5];
#pragma unroll
  for (int nt = 0; nt < 5; nt++) oacc[nt] = (f32x4)0.0f;
  unsigned short* pl = &Pl[w][0];

  // prologue: stage tile 0 into buf0
  gload16(gK0, Ks[0] + C0 * 8);
  gload16(gK1, Ks[0] + C1 * 8);
  gload16(gV0, Vs[0] + C0 * 8);
  gload16(gV1, Vs[0] + C1 * 8);
  __syncthreads();

  for (int kt = 0; kt < 10; kt++) {
    const int cur = kt & 1, nxt = cur ^ 1;
    if (kt < 9) {
      const int kv1 = (kt + 1) * 64;
      gload16(gK0 + kv1 * 64, Ks[nxt] + C0 * 8);
      gload16(gK1 + kv1 * 64, Ks[nxt] + C1 * 8);
      gload16(gV0 + kv1, Vs[nxt] + C0 * 8);
      gload16(gV1 + kv1, Vs[nxt] + C1 * 8);
    }

    f32x4 sc[4];
#pragma unroll
    for (int nt = 0; nt < 4; nt++) {
      const int row = nt * 16 + c;
      const unsigned short* kb = Ks[cur] + row * 64;
      bf16x8 k0 = __builtin_bit_cast(
          bf16x8, *(const u16x8*)(kb + ((g ^ (row & 7)) * 8)));
      bf16x8 k1 = __builtin_bit_cast(
          bf16x8, *(const u16x8*)(kb + (((4 + g) ^ (row & 7)) * 8)));
      sc[nt] = mfma16(qf0, k0, (f32x4)0.0f);
      sc[nt] = mfma16(qf1, k1, sc[nt]);
    }

    if (kt == 9) {
      const int kv0 = kt * 64;
#pragma unroll
      for (int nt = 0; nt < 4; nt++) {
        const bool valid = (kv0 + nt * 16 + c) < SEQ;
#pragma unroll
        for (int r = 0; r < 4; r++)
          sc[nt][r] = valid ? EXP2(sc[nt][r]) : 0.0f;
      }
    } else {
#pragma unroll
      for (int nt = 0; nt < 4; nt++)
#pragma unroll
        for (int r = 0; r < 4; r++) sc[nt][r] = EXP2(sc[nt][r]);
    }

#pragma unroll
    for (int nt = 0; nt < 4; nt++)
#pragma unroll
      for (int r = 0; r < 4; r++)
        pl[(g * 4 + r) * 72 + nt * 16 + c] = f2bf(sc[nt][r]);
    bf16x8 pa0 = __builtin_bit_cast(bf16x8, *(const u16x8*)(pl + c * 72 + g * 8));
    bf16x8 pa1 =
        __builtin_bit_cast(bf16x8, *(const u16x8*)(pl + c * 72 + 32 + g * 8));

#pragma unroll
    for (int nt = 0; nt < 5; nt++) {
      const int row = nt * 16 + c;
      const unsigned short* vb =
          (nt == 4) ? (Vones + c * 64) : (Vs[cur] + row * 64);
      bf16x8 v0 = __builtin_bit_cast(
          bf16x8, *(const u16x8*)(vb + ((g ^ (row & 7)) * 8)));
      bf16x8 v1 = __builtin_bit_cast(
          bf16x8, *(const u16x8*)(vb + (((4 + g) ^ (row & 7)) * 8)));
      oacc[nt] = mfma16(pa0, v0, oacc[nt]);
      oacc[nt] = mfma16(pa1, v1, oacc[nt]);
    }

    __syncthreads();  // drains prefetch (hidden under compute) + WAR
  }

#pragma unroll
  for (int r = 0; r < 4; r++) {
    int s = q0 + g * 4 + r;
    if (s >= SEQ) continue;
    float l = __shfl(oacc[4][r], lane & 48, 64);
    float inv = 1.0f / l;
#pragma unroll
    for (int nt = 0; nt < 4; nt++)
      out[((size_t)b * SEQ + s) * DM + h * HD + nt * 16 + c] =
          oacc[nt][r] * inv;
  }
}

extern "C" void kernel_launch(void* const* d_in, const int* in_sizes, int n_in,
                              void* d_out, int out_size, void* d_ws,
                              size_t ws_size, hipStream_t stream) {
  const float* x = (const float*)d_in[0];
  const float* Wq = (const float*)d_in[1];
  const float* bq = (const float*)d_in[2];
  const float* Wk = (const float*)d_in[3];
  const float* bk = (const float*)d_in[4];
  const float* Wv = (const float*)d_in[5];
  const float* bv = (const float*)d_in[6];
  float* out = (float*)d_out;

  const size_t nXB = (size_t)MTOT * DM;
  const size_t nWB = (size_t)3 * DM * DM;
  const size_t nQK = (size_t)NB * NH * SPAD * HD;
  const size_t needed = (nXB + nWB + 3 * nQK) * 2;
  if (ws_size < needed) return;

  unsigned short* xb = (unsigned short*)d_ws;
  unsigned short* wb = xb + nXB;
  unsigned short* Qb = wb + nWB;
  unsigned short* Kb = Qb + nQK;
  unsigned short* Vt = Kb + nQK;

  cvt_kernel<<<21536, 256, 0, stream>>>(x, Wq, Wk, Wv, xb, wb);
  gemm256u<<<876, 512, 0, stream>>>(xb, wb, bq, bk, bv, Qb, Kb, Vt);
  attn_kernel<<<5120, 256, 0, stream>>>(Qb, Kb, Vt, out);
}

// Round 13
// 390.982 us; speedup vs baseline: 1.0633x; 1.0633x over previous
//
#include <hip/hip_runtime.h>
#include <stdint.h>

#define NB 32
#define SEQ 577
#define SPAD 640
#define NH 16
#define HD 64
#define DM 1024
#define MTOT (NB * SEQ) /* 18464 */
#define KT_N 16         /* K-tiles of 64: 1024/64 */

typedef __bf16 bf16x8 __attribute__((ext_vector_type(8)));
typedef float f32x4 __attribute__((ext_vector_type(4)));
typedef unsigned short u16x8 __attribute__((ext_vector_type(8)));
typedef unsigned short u16x4 __attribute__((ext_vector_type(4)));

__device__ __forceinline__ unsigned short f2bf(float f) {
  unsigned int u = __builtin_bit_cast(unsigned int, f);
  return (unsigned short)((u + 0x7FFFu + ((u >> 16) & 1u)) >> 16);
}

__device__ __forceinline__ f32x4 mfma16(bf16x8 a, bf16x8 b, f32x4 c) {
  return __builtin_amdgcn_mfma_f32_16x16x32_bf16(a, b, c, 0, 0, 0);
}

__device__ __forceinline__ void gload16(const unsigned short* g, unsigned short* l) {
  __builtin_amdgcn_global_load_lds(
      (const __attribute__((address_space(1))) unsigned int*)g,
      (__attribute__((address_space(3))) unsigned int*)l, 16, 0, 0);
}

#define BC8(p) __builtin_bit_cast(bf16x8, *(const u16x8*)(p))

#if __has_builtin(__builtin_amdgcn_exp2f)
#define EXP2(x) __builtin_amdgcn_exp2f(x)
#else
#define EXP2(x) exp2f(x)
#endif

// softmax scale folded into Q at projection epilogue: 0.125 * log2(e)
#define QSCALE 0.18033688f

// ---------------- fp32 -> bf16 conversion of x and the 3 weight matrices ----
__global__ void cvt_kernel(const float* __restrict__ x,
                           const float* __restrict__ wq,
                           const float* __restrict__ wk,
                           const float* __restrict__ wv,
                           unsigned short* __restrict__ xb,
                           unsigned short* __restrict__ wb) {
  const long long NX = (long long)MTOT * DM;
  long long i = ((long long)blockIdx.x * blockDim.x + threadIdx.x) * 4;
  const float* src;
  unsigned short* dst;
  if (i < NX) {
    src = x + i;
    dst = xb + i;
  } else {
    long long j = i - NX;                 // 0 .. 3*2^20-1, DM*DM = 2^20
    int wsel = (int)(j >> 20);
    long long off = j & 0xFFFFF;
    src = (wsel == 0 ? wq : wsel == 1 ? wk : wv) + off;
    dst = wb + j;
  }
  f32x4 v = *(const f32x4*)src;
  u16x4 o;
  o.x = f2bf(v.x); o.y = f2bf(v.y); o.z = f2bf(v.z); o.w = f2bf(v.w);
  *(u16x4*)dst = o;
}

// ---------------- 256^2 BK=64 K-loop, counted-lgkm schedule (R11 revert) ----
// R12 post-mortem: BK=32 was clock-normalized identical with added bank
// conflicts and no occupancy gain -> reverted to the known-clean BK=64.
template <int MODE>
__device__ __forceinline__ void kloop256(
    unsigned short* LDS, const unsigned short* const* gA,
    const unsigned short* const* gB, f32x4 (&acc)[8][4],
    int rA0, int rB0, int ch0, int ch1) {
#define MM(ACC, AF, BF)                                   \
  do {                                                    \
    if constexpr (MODE == 0)                              \
      ACC = mfma16(AF, BF, ACC);                          \
    else                                                  \
      ACC = mfma16(BF, AF, ACC);                          \
  } while (0)
  const int t = threadIdx.x;
  for (int kt = 0; kt < KT_N; ++kt) {
    unsigned short* ab = LDS + (kt & 1) * 32768;
    unsigned short* bb = ab + 16384;
    const bool st = (kt + 2) < KT_N;
    const int ko2 = (kt + 2) * 64;
    bf16x8 af[4][2], bf0[2][2], bf1[2][2];

    // -- phase 0: reads A-lo + B01; MFMA lo x ni01
#pragma unroll
    for (int mi = 0; mi < 4; mi++) {
      const unsigned short* rp = ab + (rA0 + mi * 16) * 64;
      af[mi][0] = BC8(rp + ch0);
      af[mi][1] = BC8(rp + ch1);
    }
#pragma unroll
    for (int ni = 0; ni < 2; ni++) {
      const unsigned short* rp = bb + (rB0 + ni * 16) * 64;
      bf0[ni][0] = BC8(rp + ch0);
      bf0[ni][1] = BC8(rp + ch1);
    }
    __builtin_amdgcn_s_setprio(1);
#pragma unroll
    for (int mi = 0; mi < 4; mi++)
#pragma unroll
      for (int ni = 0; ni < 2; ni++) {
        MM(acc[mi][ni], af[mi][0], bf0[ni][0]);
        MM(acc[mi][ni], af[mi][1], bf0[ni][1]);
      }
    __builtin_amdgcn_s_setprio(0);
    asm volatile("s_waitcnt lgkmcnt(0)" ::: "memory");
    __builtin_amdgcn_s_barrier();
    __builtin_amdgcn_sched_barrier(0);

    // -- phase 1: stage A q0,q2 (read in p0); reads B23; MFMA lo x ni23
    if (st) {
      gload16(gA[0] + ko2, ab + 0 * 4096 + t * 8);
      gload16(gA[2] + ko2, ab + 2 * 4096 + t * 8);
    }
#pragma unroll
    for (int ni = 0; ni < 2; ni++) {
      const unsigned short* rp = bb + (rB0 + (2 + ni) * 16) * 64;
      bf1[ni][0] = BC8(rp + ch0);
      bf1[ni][1] = BC8(rp + ch1);
    }
    __builtin_amdgcn_s_setprio(1);
#pragma unroll
    for (int mi = 0; mi < 4; mi++)
#pragma unroll
      for (int ni = 0; ni < 2; ni++) {
        MM(acc[mi][2 + ni], af[mi][0], bf1[ni][0]);
        MM(acc[mi][2 + ni], af[mi][1], bf1[ni][1]);
      }
    __builtin_amdgcn_s_setprio(0);
    asm volatile("s_waitcnt lgkmcnt(0)" ::: "memory");
    __builtin_amdgcn_s_barrier();
    __builtin_amdgcn_sched_barrier(0);

    // -- phase 2: stage B all (read in p0/p1); reads A-hi; MFMA hi x ni23
    if (st) {
#pragma unroll
      for (int q = 0; q < 4; q++) gload16(gB[q] + ko2, bb + q * 4096 + t * 8);
    }
#pragma unroll
    for (int mi = 0; mi < 4; mi++) {
      const unsigned short* rp = ab + (rA0 + 64 + mi * 16) * 64;
      af[mi][0] = BC8(rp + ch0);
      af[mi][1] = BC8(rp + ch1);
    }
    __builtin_amdgcn_s_setprio(1);
#pragma unroll
    for (int mi = 0; mi < 4; mi++)
#pragma unroll
      for (int ni = 0; ni < 2; ni++) {
        MM(acc[4 + mi][2 + ni], af[mi][0], bf1[ni][0]);
        MM(acc[4 + mi][2 + ni], af[mi][1], bf1[ni][1]);
      }
    __builtin_amdgcn_s_setprio(0);
    asm volatile("s_waitcnt lgkmcnt(0)" ::: "memory");
    __builtin_amdgcn_s_barrier();
    __builtin_amdgcn_sched_barrier(0);

    // -- phase 3: stage A q1,q3 (read in p2); MFMA hi x ni01; counted vmcnt
    if (st) {
      gload16(gA[1] + ko2, ab + 1 * 4096 + t * 8);
      gload16(gA[3] + ko2, ab + 3 * 4096 + t * 8);
    }
    __builtin_amdgcn_s_setprio(1);
#pragma unroll
    for (int mi = 0; mi < 4; mi++)
#pragma unroll
      for (int ni = 0; ni < 2; ni++) {
        MM(acc[4 + mi][ni], af[mi][0], bf0[ni][0]);
        MM(acc[4 + mi][ni], af[mi][1], bf0[ni][1]);
      }
    __builtin_amdgcn_s_setprio(0);
    if (kt == KT_N - 2)
      asm volatile("s_waitcnt vmcnt(0)" ::: "memory");
    else
      asm volatile("s_waitcnt vmcnt(8)" ::: "memory");
    __builtin_amdgcn_s_barrier();
    __builtin_amdgcn_sched_barrier(0);
  }
#undef MM
}

// ---------------- fused Q/K/V projection (876 blocks) -----------------------
__global__ __launch_bounds__(512, 2) void gemm256u(
    const unsigned short* __restrict__ xb, const unsigned short* __restrict__ wb,
    const float* __restrict__ bq, const float* __restrict__ bk,
    const float* __restrict__ bv,
    unsigned short* __restrict__ qo, unsigned short* __restrict__ ko,
    unsigned short* __restrict__ vo) {
  __shared__ __align__(16) unsigned short LDS[65536];  // 128 KiB
  const int id = blockIdx.x;
  int m_tile, col, z;
  bool modeV;
  if (id < 584) {
    modeV = false;
    const int xcd = id & 7, j = id >> 3;
    const int p = xcd * 73 + j;       // bijective, 0..583
    m_tile = p >> 3;                  // 0..72
    col = p & 7;                      // 0..7 (col&3 -> n-block)
    z = col >> 2;                     // 0: Q, 1: K
  } else {
    modeV = true;
    const int q = id - 584;           // 0..291
    const int xcd = q & 7, j = q >> 3;
    const int p = (xcd < 4) ? xcd * 37 + j : 148 + (xcd - 4) * 36 + j;
    m_tile = p >> 2;                  // 0..72
    col = p & 3;                      // 0..3
    z = 2;
  }
  const int n0 = (modeV ? col : (col & 3)) * 256;
  const int m0 = m_tile * 256;

  const int t = threadIdx.x;        // 0..511
  const int lane = t & 63;
  const int w = t >> 6;             // 8 waves
  const int g = lane >> 4, c = lane & 15;
  const int wm = w & 1, wn = w >> 1;

  const unsigned short* W = wb + (size_t)z * (DM * DM);
  const float* bias = modeV ? bv : (z ? bk : bq);
  unsigned short* outp = modeV ? vo : (z ? ko : qo);
  const float qscale = (!modeV && z == 0) ? QSCALE : 1.0f;

  const int srow = t >> 3;
  const int schunk = (t & 7) ^ (srow & 7);
  const unsigned short* gA[4];
#pragma unroll
  for (int q = 0; q < 4; q++) {
    int rg = m0 + q * 64 + srow;
    if (rg > MTOT - 1) rg = MTOT - 1;
    gA[q] = xb + (size_t)rg * DM + schunk * 8;
  }
  const unsigned short* gB[4];
#pragma unroll
  for (int q = 0; q < 4; q++)
    gB[q] = W + (size_t)(n0 + q * 64 + srow) * DM + schunk * 8;

  const int cx = c & 7;
  const int ch0 = (g ^ cx) * 8;        // kk=0 (k 0..31)
  const int ch1 = ((4 + g) ^ cx) * 8;  // kk=1 (k 32..63)

  f32x4 acc[8][4];
#pragma unroll
  for (int mi = 0; mi < 8; mi++)
#pragma unroll
    for (int ni = 0; ni < 4; ni++) acc[mi][ni] = (f32x4)0.0f;

  // prologue: stage K-tile 0 -> buf0, K-tile 1 -> buf1 (16 issues), wait 8
#pragma unroll
  for (int q = 0; q < 4; q++) gload16(gA[q], LDS + q * 4096 + t * 8);
#pragma unroll
  for (int q = 0; q < 4; q++) gload16(gB[q], LDS + 16384 + q * 4096 + t * 8);
#pragma unroll
  for (int q = 0; q < 4; q++) gload16(gA[q] + 64, LDS + 32768 + q * 4096 + t * 8);
#pragma unroll
  for (int q = 0; q < 4; q++)
    gload16(gB[q] + 64, LDS + 32768 + 16384 + q * 4096 + t * 8);
  asm volatile("s_waitcnt vmcnt(8)" ::: "memory");
  __builtin_amdgcn_s_barrier();
  __builtin_amdgcn_sched_barrier(0);

  const int rA0 = wm * 128 + c;
  const int rB0 = wn * 64 + c;

  if (!modeV)
    kloop256<0>(LDS, gA, gB, acc, rA0, rB0, ch0, ch1);
  else
    kloop256<1>(LDS, gA, gB, acc, rA0, rB0, ch0, ch1);

  if (!modeV) {
    float bias4[4];
#pragma unroll
    for (int ni = 0; ni < 4; ni++) bias4[ni] = bias[n0 + wn * 64 + ni * 16 + c];
#pragma unroll
    for (int mi = 0; mi < 8; mi++) {
      int mb = m0 + wm * 128 + mi * 16 + g * 4;
#pragma unroll
      for (int r = 0; r < 4; r++) {
        int m = mb + r;
        if (m >= MTOT) continue;
        int bi = m / SEQ;
        int s = m - bi * SEQ;
#pragma unroll
        for (int ni = 0; ni < 4; ni++) {
          int n = n0 + wn * 64 + ni * 16 + c;
          int hh = n >> 6, dd = n & 63;
          outp[(((size_t)bi * NH + hh) * SPAD + s) * HD + dd] =
              f2bf((acc[mi][ni][r] + bias4[ni]) * qscale);
        }
      }
    }
  } else {
#pragma unroll
    for (int ni = 0; ni < 4; ni++) {
#pragma unroll
      for (int r = 0; r < 4; r++) {
        int n = n0 + wn * 64 + ni * 16 + g * 4 + r;
        int hh = n >> 6, dd = n & 63;
        float bn = bias[n];
#pragma unroll
        for (int mi = 0; mi < 8; mi++) {
          int m = m0 + wm * 128 + mi * 16 + c;
          if (m >= MTOT) continue;
          int bi = m / SEQ;
          int s = m - bi * SEQ;
          outp[(((size_t)bi * NH + hh) * HD + dd) * SPAD + s] =
              f2bf(acc[mi][ni][r] + bn);
        }
      }
    }
  }
}

// ---------------- flash attention v2, R12: swapped QK^T + packed P ----------
// Swapped QK (mfma(K,Q)): lane (g,c) reg r of sc[nt] = P[q=c][kv=nt*16+g*4+r]
// -> each lane's 4 values per nt are kv-CONTIGUOUS: pack via f2bf (bit-
// identical numerics) into uint2, store with 4 ds_write_b64 (was 16 b16).
// XOR swizzle: phys 4-chunk = (nt*4+g) ^ (2*(c&7)); read-back pa0/pa1 as
// b128 at phys 8-chunk (g^(c&7)) / ((4+g)^(c&7)) -- <=2-way banks both ways.
// P-row sum now in-lane: lsum += sum(sc) per iter, 2 shfl_xor at the end
// -> Vones + 5th PV MFMA + 2 b128 reads eliminated. LDS 44->40 KB ->
// 4 blocks/CU. PV core, oacc layout, output indexing unchanged.
__global__ __launch_bounds__(256, 4) void attn_kernel(
    const unsigned short* __restrict__ Qb, const unsigned short* __restrict__ Kb,
    const unsigned short* __restrict__ Vt, float* __restrict__ out) {
  __shared__ __align__(16) unsigned short Ks[2][64 * 64];   // [buf][kv][d], swizzled
  __shared__ __align__(16) unsigned short Vs[2][64 * 64];   // [buf][d][kv], swizzled
  __shared__ __align__(16) unsigned short Pl[4][16 * 64];   // [wave][q][kv], swizzled
  const int t = threadIdx.x, lane = t & 63, w = t >> 6;
  const int g = lane >> 4, c = lane & 15;

  const int id = blockIdx.x;          // 0..5119
  const int xcd = id & 7;
  const int slot = id >> 3;           // 0..639
  const int qt = slot % 10;
  const int pairIdx = slot / 10;      // 0..63
  const int pair = xcd * 64 + pairIdx;
  const int b = pair >> 4;
  const int h = pair & 15;

  const int q0 = qt * 64 + w * 16;
  const size_t bh = (size_t)b * NH + h;
  const unsigned short* Qp = Qb + bh * SPAD * HD;
  const unsigned short* Kp = Kb + bh * SPAD * HD;
  const unsigned short* Vp = Vt + bh * HD * SPAD;

  bf16x8 qf0 = __builtin_bit_cast(
      bf16x8, *(const u16x8*)(Qp + (size_t)(q0 + c) * HD + g * 8));
  bf16x8 qf1 = __builtin_bit_cast(
      bf16x8, *(const u16x8*)(Qp + (size_t)(q0 + c) * HD + 32 + g * 8));

  const int C0 = t, C1 = t + 256;
  const int r0 = C0 >> 3, cg0 = (C0 & 7) ^ (r0 & 7);
  const int r1 = C1 >> 3, cg1 = (C1 & 7) ^ (r1 & 7);
  const unsigned short* gK0 = Kp + (size_t)(r0 * 8 + cg0) * 8;
  const unsigned short* gK1 = Kp + (size_t)(r1 * 8 + cg1) * 8;
  const unsigned short* gV0 = Vp + (size_t)r0 * SPAD + cg0 * 8;
  const unsigned short* gV1 = Vp + (size_t)r1 * SPAD + cg1 * 8;

  f32x4 oacc[4];
#pragma unroll
  for (int nt = 0; nt < 4; nt++) oacc[nt] = (f32x4)0.0f;
  float lsum = 0.0f;
  unsigned short* pl = &Pl[w][0];

  // P store/read swizzle constants
  const int pbase = c * 64;                 // row q = c, 64 shorts/row
  const int psw2 = (c & 7) << 1;            // 4-chunk XOR
  const int rd0 = (g ^ (c & 7)) * 8;        // pa0 8-chunk
  const int rd1 = ((4 + g) ^ (c & 7)) * 8;  // pa1 8-chunk

  // prologue: stage tile 0 into buf0
  gload16(gK0, Ks[0] + C0 * 8);
  gload16(gK1, Ks[0] + C1 * 8);
  gload16(gV0, Vs[0] + C0 * 8);
  gload16(gV1, Vs[0] + C1 * 8);
  __syncthreads();

  for (int kt = 0; kt < 10; kt++) {
    const int cur = kt & 1, nxt = cur ^ 1;
    if (kt < 9) {
      const int kv1 = (kt + 1) * 64;
      gload16(gK0 + kv1 * 64, Ks[nxt] + C0 * 8);
      gload16(gK1 + kv1 * 64, Ks[nxt] + C1 * 8);
      gload16(gV0 + kv1, Vs[nxt] + C0 * 8);
      gload16(gV1 + kv1, Vs[nxt] + C1 * 8);
    }

    // QK^T, swapped operands: sc[nt][r] = S[q=c][kv=nt*16+g*4+r]
    f32x4 sc[4];
#pragma unroll
    for (int nt = 0; nt < 4; nt++) {
      const int row = nt * 16 + c;
      const unsigned short* kb = Ks[cur] + row * 64;
      bf16x8 k0 = __builtin_bit_cast(
          bf16x8, *(const u16x8*)(kb + ((g ^ (row & 7)) * 8)));
      bf16x8 k1 = __builtin_bit_cast(
          bf16x8, *(const u16x8*)(kb + (((4 + g) ^ (row & 7)) * 8)));
      sc[nt] = mfma16(k0, qf0, (f32x4)0.0f);
      sc[nt] = mfma16(k1, qf1, sc[nt]);
    }

    if (kt == 9) {
#pragma unroll
      for (int nt = 0; nt < 4; nt++)
#pragma unroll
        for (int r = 0; r < 4; r++) {
          const bool valid = (576 + nt * 16 + g * 4 + r) < SEQ;
          sc[nt][r] = valid ? EXP2(sc[nt][r]) : 0.0f;
        }
    } else {
#pragma unroll
      for (int nt = 0; nt < 4; nt++)
#pragma unroll
        for (int r = 0; r < 4; r++) sc[nt][r] = EXP2(sc[nt][r]);
    }

    // row-sum (in-lane) + packed P store: 4x ds_write_b64
#pragma unroll
    for (int nt = 0; nt < 4; nt++) {
      lsum += sc[nt][0] + sc[nt][1] + sc[nt][2] + sc[nt][3];
      unsigned pk0 = (unsigned)f2bf(sc[nt][0]) | ((unsigned)f2bf(sc[nt][1]) << 16);
      unsigned pk1 = (unsigned)f2bf(sc[nt][2]) | ((unsigned)f2bf(sc[nt][3]) << 16);
      const int ch4 = (nt * 4 + g) ^ psw2;
      uint2 pv2 = {pk0, pk1};
      *(uint2*)(pl + pbase + ch4 * 4) = pv2;
    }
    bf16x8 pa0 = BC8(pl + pbase + rd0);
    bf16x8 pa1 = BC8(pl + pbase + rd1);

    // PV (4 output d-tiles; ones-row trick removed)
#pragma unroll
    for (int nt = 0; nt < 4; nt++) {
      const int row = nt * 16 + c;
      const unsigned short* vb = Vs[cur] + row * 64;
      bf16x8 v0 = __builtin_bit_cast(
          bf16x8, *(const u16x8*)(vb + ((g ^ (row & 7)) * 8)));
      bf16x8 v1 = __builtin_bit_cast(
          bf16x8, *(const u16x8*)(vb + (((4 + g) ^ (row & 7)) * 8)));
      oacc[nt] = mfma16(pa0, v0, oacc[nt]);
      oacc[nt] = mfma16(pa1, v1, oacc[nt]);
    }

    __syncthreads();  // drains prefetch (hidden under compute) + WAR
  }

  // finish l: reduce across the 4 g-groups (lane c holds q=c partial)
  lsum += __shfl_xor(lsum, 16, 64);
  lsum += __shfl_xor(lsum, 32, 64);

#pragma unroll
  for (int r = 0; r < 4; r++) {
    int s = q0 + g * 4 + r;
    if (s >= SEQ) continue;
    float l = __shfl(lsum, (lane & 48) | (g * 4 + r), 64);
    float inv = 1.0f / l;
#pragma unroll
    for (int nt = 0; nt < 4; nt++)
      out[((size_t)b * SEQ + s) * DM + h * HD + nt * 16 + c] =
          oacc[nt][r] * inv;
  }
}

extern "C" void kernel_launch(void* const* d_in, const int* in_sizes, int n_in,
                              void* d_out, int out_size, void* d_ws,
                              size_t ws_size, hipStream_t stream) {
  const float* x = (const float*)d_in[0];
  const float* Wq = (const float*)d_in[1];
  const float* bq = (const float*)d_in[2];
  const float* Wk = (const float*)d_in[3];
  const float* bk = (const float*)d_in[4];
  const float* Wv = (const float*)d_in[5];
  const float* bv = (const float*)d_in[6];
  float* out = (float*)d_out;

  const size_t nXB = (size_t)MTOT * DM;
  const size_t nWB = (size_t)3 * DM * DM;
  const size_t nQK = (size_t)NB * NH * SPAD * HD;
  const size_t needed = (nXB + nWB + 3 * nQK) * 2;
  if (ws_size < needed) return;

  unsigned short* xb = (unsigned short*)d_ws;
  unsigned short* wb = xb + nXB;
  unsigned short* Qb = wb + nWB;
  unsigned short* Kb = Qb + nQK;
  unsigned short* Vt = Kb + nQK;

  cvt_kernel<<<21536, 256, 0, stream>>>(x, Wq, Wk, Wv, xb, wb);
  gemm256u<<<876, 512, 0, stream>>>(xb, wb, bq, bk, bv, Qb, Kb, Vt);
  attn_kernel<<<5120, 256, 0, stream>>>(Qb, Kb, Vt, out);
}

// Round 14
// 385.192 us; speedup vs baseline: 1.0793x; 1.0150x over previous
//
#include <hip/hip_runtime.h>
#include <stdint.h>

#define NB 32
#define SEQ 577
#define SPAD 640
#define NH 16
#define HD 64
#define DM 1024
#define MTOT (NB * SEQ) /* 18464 */
#define KT_N 16         /* K-tiles of 64: 1024/64 */

typedef __bf16 bf16x8 __attribute__((ext_vector_type(8)));
typedef float f32x4 __attribute__((ext_vector_type(4)));
typedef unsigned short u16x8 __attribute__((ext_vector_type(8)));
typedef unsigned short u16x4 __attribute__((ext_vector_type(4)));

__device__ __forceinline__ unsigned short f2bf(float f) {
  unsigned int u = __builtin_bit_cast(unsigned int, f);
  return (unsigned short)((u + 0x7FFFu + ((u >> 16) & 1u)) >> 16);
}

__device__ __forceinline__ float bf2f(unsigned short u) {
  return __builtin_bit_cast(float, (unsigned int)u << 16);
}

__device__ __forceinline__ f32x4 mfma16(bf16x8 a, bf16x8 b, f32x4 c) {
  return __builtin_amdgcn_mfma_f32_16x16x32_bf16(a, b, c, 0, 0, 0);
}

__device__ __forceinline__ void gload16(const unsigned short* g, unsigned short* l) {
  __builtin_amdgcn_global_load_lds(
      (const __attribute__((address_space(1))) unsigned int*)g,
      (__attribute__((address_space(3))) unsigned int*)l, 16, 0, 0);
}

#define BC8(p) __builtin_bit_cast(bf16x8, *(const u16x8*)(p))

#if __has_builtin(__builtin_amdgcn_exp2f)
#define EXP2(x) __builtin_amdgcn_exp2f(x)
#else
#define EXP2(x) exp2f(x)
#endif

// softmax scale folded into Q at projection epilogue: 0.125 * log2(e)
#define QSCALE 0.18033688f

// ---------------- fp32 -> bf16 conversion of x and the 3 weight matrices ----
__global__ void cvt_kernel(const float* __restrict__ x,
                           const float* __restrict__ wq,
                           const float* __restrict__ wk,
                           const float* __restrict__ wv,
                           unsigned short* __restrict__ xb,
                           unsigned short* __restrict__ wb) {
  const long long NX = (long long)MTOT * DM;
  long long i = ((long long)blockIdx.x * blockDim.x + threadIdx.x) * 4;
  const float* src;
  unsigned short* dst;
  if (i < NX) {
    src = x + i;
    dst = xb + i;
  } else {
    long long j = i - NX;                 // 0 .. 3*2^20-1, DM*DM = 2^20
    int wsel = (int)(j >> 20);
    long long off = j & 0xFFFFF;
    src = (wsel == 0 ? wq : wsel == 1 ? wk : wv) + off;
    dst = wb + j;
  }
  f32x4 v = *(const f32x4*)src;
  u16x4 o;
  o.x = f2bf(v.x); o.y = f2bf(v.y); o.z = f2bf(v.z); o.w = f2bf(v.w);
  *(u16x4*)dst = o;
}

// ---------------- 256^2 BK=64 K-loop, counted-lgkm schedule (frozen) --------
template <int MODE>
__device__ __forceinline__ void kloop256(
    unsigned short* LDS, const unsigned short* const* gA,
    const unsigned short* const* gB, f32x4 (&acc)[8][4],
    int rA0, int rB0, int ch0, int ch1) {
#define MM(ACC, AF, BF)                                   \
  do {                                                    \
    if constexpr (MODE == 0)                              \
      ACC = mfma16(AF, BF, ACC);                          \
    else                                                  \
      ACC = mfma16(BF, AF, ACC);                          \
  } while (0)
  const int t = threadIdx.x;
  for (int kt = 0; kt < KT_N; ++kt) {
    unsigned short* ab = LDS + (kt & 1) * 32768;
    unsigned short* bb = ab + 16384;
    const bool st = (kt + 2) < KT_N;
    const int ko2 = (kt + 2) * 64;
    bf16x8 af[4][2], bf0[2][2], bf1[2][2];

    // -- phase 0: reads A-lo + B01; MFMA lo x ni01
#pragma unroll
    for (int mi = 0; mi < 4; mi++) {
      const unsigned short* rp = ab + (rA0 + mi * 16) * 64;
      af[mi][0] = BC8(rp + ch0);
      af[mi][1] = BC8(rp + ch1);
    }
#pragma unroll
    for (int ni = 0; ni < 2; ni++) {
      const unsigned short* rp = bb + (rB0 + ni * 16) * 64;
      bf0[ni][0] = BC8(rp + ch0);
      bf0[ni][1] = BC8(rp + ch1);
    }
    __builtin_amdgcn_s_setprio(1);
#pragma unroll
    for (int mi = 0; mi < 4; mi++)
#pragma unroll
      for (int ni = 0; ni < 2; ni++) {
        MM(acc[mi][ni], af[mi][0], bf0[ni][0]);
        MM(acc[mi][ni], af[mi][1], bf0[ni][1]);
      }
    __builtin_amdgcn_s_setprio(0);
    asm volatile("s_waitcnt lgkmcnt(0)" ::: "memory");
    __builtin_amdgcn_s_barrier();
    __builtin_amdgcn_sched_barrier(0);

    // -- phase 1: stage A q0,q2 (read in p0); reads B23; MFMA lo x ni23
    if (st) {
      gload16(gA[0] + ko2, ab + 0 * 4096 + t * 8);
      gload16(gA[2] + ko2, ab + 2 * 4096 + t * 8);
    }
#pragma unroll
    for (int ni = 0; ni < 2; ni++) {
      const unsigned short* rp = bb + (rB0 + (2 + ni) * 16) * 64;
      bf1[ni][0] = BC8(rp + ch0);
      bf1[ni][1] = BC8(rp + ch1);
    }
    __builtin_amdgcn_s_setprio(1);
#pragma unroll
    for (int mi = 0; mi < 4; mi++)
#pragma unroll
      for (int ni = 0; ni < 2; ni++) {
        MM(acc[mi][2 + ni], af[mi][0], bf1[ni][0]);
        MM(acc[mi][2 + ni], af[mi][1], bf1[ni][1]);
      }
    __builtin_amdgcn_s_setprio(0);
    asm volatile("s_waitcnt lgkmcnt(0)" ::: "memory");
    __builtin_amdgcn_s_barrier();
    __builtin_amdgcn_sched_barrier(0);

    // -- phase 2: stage B all (read in p0/p1); reads A-hi; MFMA hi x ni23
    if (st) {
#pragma unroll
      for (int q = 0; q < 4; q++) gload16(gB[q] + ko2, bb + q * 4096 + t * 8);
    }
#pragma unroll
    for (int mi = 0; mi < 4; mi++) {
      const unsigned short* rp = ab + (rA0 + 64 + mi * 16) * 64;
      af[mi][0] = BC8(rp + ch0);
      af[mi][1] = BC8(rp + ch1);
    }
    __builtin_amdgcn_s_setprio(1);
#pragma unroll
    for (int mi = 0; mi < 4; mi++)
#pragma unroll
      for (int ni = 0; ni < 2; ni++) {
        MM(acc[4 + mi][2 + ni], af[mi][0], bf1[ni][0]);
        MM(acc[4 + mi][2 + ni], af[mi][1], bf1[ni][1]);
      }
    __builtin_amdgcn_s_setprio(0);
    asm volatile("s_waitcnt lgkmcnt(0)" ::: "memory");
    __builtin_amdgcn_s_barrier();
    __builtin_amdgcn_sched_barrier(0);

    // -- phase 3: stage A q1,q3 (read in p2); MFMA hi x ni01; counted vmcnt
    if (st) {
      gload16(gA[1] + ko2, ab + 1 * 4096 + t * 8);
      gload16(gA[3] + ko2, ab + 3 * 4096 + t * 8);
    }
    __builtin_amdgcn_s_setprio(1);
#pragma unroll
    for (int mi = 0; mi < 4; mi++)
#pragma unroll
      for (int ni = 0; ni < 2; ni++) {
        MM(acc[4 + mi][ni], af[mi][0], bf0[ni][0]);
        MM(acc[4 + mi][ni], af[mi][1], bf0[ni][1]);
      }
    __builtin_amdgcn_s_setprio(0);
    if (kt == KT_N - 2)
      asm volatile("s_waitcnt vmcnt(0)" ::: "memory");
    else
      asm volatile("s_waitcnt vmcnt(8)" ::: "memory");
    __builtin_amdgcn_s_barrier();
    __builtin_amdgcn_sched_barrier(0);
  }
#undef MM
}

// ---------------- fused Q/K/V projection (876 blocks, frozen) ---------------
__global__ __launch_bounds__(512, 2) void gemm256u(
    const unsigned short* __restrict__ xb, const unsigned short* __restrict__ wb,
    const float* __restrict__ bq, const float* __restrict__ bk,
    const float* __restrict__ bv,
    unsigned short* __restrict__ qo, unsigned short* __restrict__ ko,
    unsigned short* __restrict__ vo) {
  __shared__ __align__(16) unsigned short LDS[65536];  // 128 KiB
  const int id = blockIdx.x;
  int m_tile, col, z;
  bool modeV;
  if (id < 584) {
    modeV = false;
    const int xcd = id & 7, j = id >> 3;
    const int p = xcd * 73 + j;       // bijective, 0..583
    m_tile = p >> 3;                  // 0..72
    col = p & 7;                      // 0..7 (col&3 -> n-block)
    z = col >> 2;                     // 0: Q, 1: K
  } else {
    modeV = true;
    const int q = id - 584;           // 0..291
    const int xcd = q & 7, j = q >> 3;
    const int p = (xcd < 4) ? xcd * 37 + j : 148 + (xcd - 4) * 36 + j;
    m_tile = p >> 2;                  // 0..72
    col = p & 3;                      // 0..3
    z = 2;
  }
  const int n0 = (modeV ? col : (col & 3)) * 256;
  const int m0 = m_tile * 256;

  const int t = threadIdx.x;        // 0..511
  const int lane = t & 63;
  const int w = t >> 6;             // 8 waves
  const int g = lane >> 4, c = lane & 15;
  const int wm = w & 1, wn = w >> 1;

  const unsigned short* W = wb + (size_t)z * (DM * DM);
  const float* bias = modeV ? bv : (z ? bk : bq);
  unsigned short* outp = modeV ? vo : (z ? ko : qo);
  const float qscale = (!modeV && z == 0) ? QSCALE : 1.0f;

  const int srow = t >> 3;
  const int schunk = (t & 7) ^ (srow & 7);
  const unsigned short* gA[4];
#pragma unroll
  for (int q = 0; q < 4; q++) {
    int rg = m0 + q * 64 + srow;
    if (rg > MTOT - 1) rg = MTOT - 1;
    gA[q] = xb + (size_t)rg * DM + schunk * 8;
  }
  const unsigned short* gB[4];
#pragma unroll
  for (int q = 0; q < 4; q++)
    gB[q] = W + (size_t)(n0 + q * 64 + srow) * DM + schunk * 8;

  const int cx = c & 7;
  const int ch0 = (g ^ cx) * 8;        // kk=0 (k 0..31)
  const int ch1 = ((4 + g) ^ cx) * 8;  // kk=1 (k 32..63)

  f32x4 acc[8][4];
#pragma unroll
  for (int mi = 0; mi < 8; mi++)
#pragma unroll
    for (int ni = 0; ni < 4; ni++) acc[mi][ni] = (f32x4)0.0f;

  // prologue: stage K-tile 0 -> buf0, K-tile 1 -> buf1 (16 issues), wait 8
#pragma unroll
  for (int q = 0; q < 4; q++) gload16(gA[q], LDS + q * 4096 + t * 8);
#pragma unroll
  for (int q = 0; q < 4; q++) gload16(gB[q], LDS + 16384 + q * 4096 + t * 8);
#pragma unroll
  for (int q = 0; q < 4; q++) gload16(gA[q] + 64, LDS + 32768 + q * 4096 + t * 8);
#pragma unroll
  for (int q = 0; q < 4; q++)
    gload16(gB[q] + 64, LDS + 32768 + 16384 + q * 4096 + t * 8);
  asm volatile("s_waitcnt vmcnt(8)" ::: "memory");
  __builtin_amdgcn_s_barrier();
  __builtin_amdgcn_sched_barrier(0);

  const int rA0 = wm * 128 + c;
  const int rB0 = wn * 64 + c;

  if (!modeV)
    kloop256<0>(LDS, gA, gB, acc, rA0, rB0, ch0, ch1);
  else
    kloop256<1>(LDS, gA, gB, acc, rA0, rB0, ch0, ch1);

  if (!modeV) {
    float bias4[4];
#pragma unroll
    for (int ni = 0; ni < 4; ni++) bias4[ni] = bias[n0 + wn * 64 + ni * 16 + c];
#pragma unroll
    for (int mi = 0; mi < 8; mi++) {
      int mb = m0 + wm * 128 + mi * 16 + g * 4;
#pragma unroll
      for (int r = 0; r < 4; r++) {
        int m = mb + r;
        if (m >= MTOT) continue;
        int bi = m / SEQ;
        int s = m - bi * SEQ;
#pragma unroll
        for (int ni = 0; ni < 4; ni++) {
          int n = n0 + wn * 64 + ni * 16 + c;
          int hh = n >> 6, dd = n & 63;
          outp[(((size_t)bi * NH + hh) * SPAD + s) * HD + dd] =
              f2bf((acc[mi][ni][r] + bias4[ni]) * qscale);
        }
      }
    }
  } else {
#pragma unroll
    for (int ni = 0; ni < 4; ni++) {
#pragma unroll
      for (int r = 0; r < 4; r++) {
        int n = n0 + wn * 64 + ni * 16 + g * 4 + r;
        int hh = n >> 6, dd = n & 63;
        float bn = bias[n];
#pragma unroll
        for (int mi = 0; mi < 8; mi++) {
          int m = m0 + wm * 128 + mi * 16 + c;
          if (m >= MTOT) continue;
          int bi = m / SEQ;
          int s = m - bi * SEQ;
          outp[(((size_t)bi * NH + hh) * HD + dd) * SPAD + s] =
              f2bf(acc[mi][ni][r] + bn);
        }
      }
    }
  }
}

// ---------------- flash attention v2, R13: 9 tiles + kv=576 epilogue --------
// SEQ=577 = 9*64 + 1: tile 9 had ONE valid kv row but paid a full iteration
// (staging, 16 MFMA, 16 exp, all LDS ops). Main loop now runs 9 all-valid
// tiles (masked branch deleted); kv=576 handled by a closed-form epilogue:
// per-lane f32 dot from register-resident qf + one global K-row, 2 shfl_xor
// over g, p=exp2(s) added to lsum AFTER the g-reduction (p is g-uniform;
// adding before would 4x-count), O += shfl(p,q)*V[576][d] from global.
// Garbage-Q rows (q>=577) stay per-lane/per-r isolated and are discarded
// at the store, as before.
__global__ __launch_bounds__(256, 4) void attn_kernel(
    const unsigned short* __restrict__ Qb, const unsigned short* __restrict__ Kb,
    const unsigned short* __restrict__ Vt, float* __restrict__ out) {
  __shared__ __align__(16) unsigned short Ks[2][64 * 64];   // [buf][kv][d], swizzled
  __shared__ __align__(16) unsigned short Vs[2][64 * 64];   // [buf][d][kv], swizzled
  __shared__ __align__(16) unsigned short Pl[4][16 * 64];   // [wave][q][kv], swizzled
  const int t = threadIdx.x, lane = t & 63, w = t >> 6;
  const int g = lane >> 4, c = lane & 15;

  const int id = blockIdx.x;          // 0..5119
  const int xcd = id & 7;
  const int slot = id >> 3;           // 0..639
  const int qt = slot % 10;
  const int pairIdx = slot / 10;      // 0..63
  const int pair = xcd * 64 + pairIdx;
  const int b = pair >> 4;
  const int h = pair & 15;

  const int q0 = qt * 64 + w * 16;
  const size_t bh = (size_t)b * NH + h;
  const unsigned short* Qp = Qb + bh * SPAD * HD;
  const unsigned short* Kp = Kb + bh * SPAD * HD;
  const unsigned short* Vp = Vt + bh * HD * SPAD;

  bf16x8 qf0 = __builtin_bit_cast(
      bf16x8, *(const u16x8*)(Qp + (size_t)(q0 + c) * HD + g * 8));
  bf16x8 qf1 = __builtin_bit_cast(
      bf16x8, *(const u16x8*)(Qp + (size_t)(q0 + c) * HD + 32 + g * 8));

  const int C0 = t, C1 = t + 256;
  const int r0 = C0 >> 3, cg0 = (C0 & 7) ^ (r0 & 7);
  const int r1 = C1 >> 3, cg1 = (C1 & 7) ^ (r1 & 7);
  const unsigned short* gK0 = Kp + (size_t)(r0 * 8 + cg0) * 8;
  const unsigned short* gK1 = Kp + (size_t)(r1 * 8 + cg1) * 8;
  const unsigned short* gV0 = Vp + (size_t)r0 * SPAD + cg0 * 8;
  const unsigned short* gV1 = Vp + (size_t)r1 * SPAD + cg1 * 8;

  f32x4 oacc[4];
#pragma unroll
  for (int nt = 0; nt < 4; nt++) oacc[nt] = (f32x4)0.0f;
  float lsum = 0.0f;
  unsigned short* pl = &Pl[w][0];

  // P store/read swizzle constants
  const int pbase = c * 64;                 // row q = c, 64 shorts/row
  const int psw2 = (c & 7) << 1;            // 4-chunk XOR
  const int rd0 = (g ^ (c & 7)) * 8;        // pa0 8-chunk
  const int rd1 = ((4 + g) ^ (c & 7)) * 8;  // pa1 8-chunk

  // prologue: stage tile 0 into buf0
  gload16(gK0, Ks[0] + C0 * 8);
  gload16(gK1, Ks[0] + C1 * 8);
  gload16(gV0, Vs[0] + C0 * 8);
  gload16(gV1, Vs[0] + C1 * 8);
  __syncthreads();

  for (int kt = 0; kt < 9; kt++) {
    const int cur = kt & 1, nxt = cur ^ 1;
    if (kt < 8) {
      const int kv1 = (kt + 1) * 64;
      gload16(gK0 + kv1 * 64, Ks[nxt] + C0 * 8);
      gload16(gK1 + kv1 * 64, Ks[nxt] + C1 * 8);
      gload16(gV0 + kv1, Vs[nxt] + C0 * 8);
      gload16(gV1 + kv1, Vs[nxt] + C1 * 8);
    }

    // QK^T, swapped operands: sc[nt][r] = S[q=c][kv=nt*16+g*4+r]
    f32x4 sc[4];
#pragma unroll
    for (int nt = 0; nt < 4; nt++) {
      const int row = nt * 16 + c;
      const unsigned short* kb = Ks[cur] + row * 64;
      bf16x8 k0 = __builtin_bit_cast(
          bf16x8, *(const u16x8*)(kb + ((g ^ (row & 7)) * 8)));
      bf16x8 k1 = __builtin_bit_cast(
          bf16x8, *(const u16x8*)(kb + (((4 + g) ^ (row & 7)) * 8)));
      sc[nt] = mfma16(k0, qf0, (f32x4)0.0f);
      sc[nt] = mfma16(k1, qf1, sc[nt]);
    }

#pragma unroll
    for (int nt = 0; nt < 4; nt++)
#pragma unroll
      for (int r = 0; r < 4; r++) sc[nt][r] = EXP2(sc[nt][r]);

    // row-sum (in-lane) + packed P store: 4x ds_write_b64
#pragma unroll
    for (int nt = 0; nt < 4; nt++) {
      lsum += sc[nt][0] + sc[nt][1] + sc[nt][2] + sc[nt][3];
      unsigned pk0 = (unsigned)f2bf(sc[nt][0]) | ((unsigned)f2bf(sc[nt][1]) << 16);
      unsigned pk1 = (unsigned)f2bf(sc[nt][2]) | ((unsigned)f2bf(sc[nt][3]) << 16);
      const int ch4 = (nt * 4 + g) ^ psw2;
      uint2 pv2 = {pk0, pk1};
      *(uint2*)(pl + pbase + ch4 * 4) = pv2;
    }
    bf16x8 pa0 = BC8(pl + pbase + rd0);
    bf16x8 pa1 = BC8(pl + pbase + rd1);

    // PV (4 output d-tiles)
#pragma unroll
    for (int nt = 0; nt < 4; nt++) {
      const int row = nt * 16 + c;
      const unsigned short* vb = Vs[cur] + row * 64;
      bf16x8 v0 = __builtin_bit_cast(
          bf16x8, *(const u16x8*)(vb + ((g ^ (row & 7)) * 8)));
      bf16x8 v1 = __builtin_bit_cast(
          bf16x8, *(const u16x8*)(vb + (((4 + g) ^ (row & 7)) * 8)));
      oacc[nt] = mfma16(pa0, v0, oacc[nt]);
      oacc[nt] = mfma16(pa1, v1, oacc[nt]);
    }

    __syncthreads();  // drains prefetch (hidden under compute) + WAR
  }

  // finish l over the 9 staged tiles (kv 0..575)
  lsum += __shfl_xor(lsum, 16, 64);
  lsum += __shfl_xor(lsum, 32, 64);

  // ---- epilogue: kv = 576 (the single valid row of the 10th tile) ----
  {
    const unsigned short* krow = Kp + (size_t)576 * HD;
    bf16x8 k0 = BC8(krow + g * 8);
    bf16x8 k1 = BC8(krow + 32 + g * 8);
    float s = 0.0f;
#pragma unroll
    for (int i = 0; i < 8; i++) {
      s += (float)qf0[i] * (float)k0[i];
      s += (float)qf1[i] * (float)k1[i];
    }
    s += __shfl_xor(s, 16, 64);
    s += __shfl_xor(s, 32, 64);   // full dot over d; g-uniform now
    float p = EXP2(s);            // Q pre-scaled -> exp2 direct
    lsum += p;                    // post-reduction: counted exactly once
#pragma unroll
    for (int nt = 0; nt < 4; nt++) {
      float v = bf2f(Vp[(size_t)(nt * 16 + c) * SPAD + 576]);
#pragma unroll
      for (int r = 0; r < 4; r++) {
        float pr = __shfl(p, g * 4 + r, 64);  // p for q = g*4+r
        oacc[nt][r] += pr * v;
      }
    }
  }

#pragma unroll
  for (int r = 0; r < 4; r++) {
    int s = q0 + g * 4 + r;
    if (s >= SEQ) continue;
    float l = __shfl(lsum, (lane & 48) | (g * 4 + r), 64);
    float inv = 1.0f / l;
#pragma unroll
    for (int nt = 0; nt < 4; nt++)
      out[((size_t)b * SEQ + s) * DM + h * HD + nt * 16 + c] =
          oacc[nt][r] * inv;
  }
}

extern "C" void kernel_launch(void* const* d_in, const int* in_sizes, int n_in,
                              void* d_out, int out_size, void* d_ws,
                              size_t ws_size, hipStream_t stream) {
  const float* x = (const float*)d_in[0];
  const float* Wq = (const float*)d_in[1];
  const float* bq = (const float*)d_in[2];
  const float* Wk = (const float*)d_in[3];
  const float* bk = (const float*)d_in[4];
  const float* Wv = (const float*)d_in[5];
  const float* bv = (const float*)d_in[6];
  float* out = (float*)d_out;

  const size_t nXB = (size_t)MTOT * DM;
  const size_t nWB = (size_t)3 * DM * DM;
  const size_t nQK = (size_t)NB * NH * SPAD * HD;
  const size_t needed = (nXB + nWB + 3 * nQK) * 2;
  if (ws_size < needed) return;

  unsigned short* xb = (unsigned short*)d_ws;
  unsigned short* wb = xb + nXB;
  unsigned short* Qb = wb + nWB;
  unsigned short* Kb = Qb + nQK;
  unsigned short* Vt = Kb + nQK;

  cvt_kernel<<<21536, 256, 0, stream>>>(x, Wq, Wk, Wv, xb, wb);
  gemm256u<<<876, 512, 0, stream>>>(xb, wb, bq, bk, bv, Qb, Kb, Vt);
  attn_kernel<<<5120, 256, 0, stream>>>(Qb, Kb, Vt, out);
}